// Round 1
// baseline (298.441 us; speedup 1.0000x reference)
//
#include <hip/hip_runtime.h>
#include <hip/hip_bf16.h>

// SlicingLinearBlock: out[16384,4096] = x[16384,256] @ B[256,4096] (fp32),
// where B[k,o] = W[k/8, o, k%8].  Strategy: pre-convert x and W to bf16 in
// d_ws, then m97-style 128x128 bf16 MFMA GEMM with global_load_lds staging.
//
// Workspace layout (d_ws): [0, 8MB) x_bf16 [16384,256]; [8MB, 10MB) Bt_bf16 [4096,256].

typedef __attribute__((ext_vector_type(8)))  __bf16          bf16x8;
typedef __attribute__((ext_vector_type(8)))  unsigned short  ushort8;
typedef __attribute__((ext_vector_type(4)))  float           floatx4;

__device__ __forceinline__ unsigned short f2bf(float f) {
    union { float f; unsigned u; } v; v.f = f;
    unsigned r = v.u + 0x7fffu + ((v.u >> 16) & 1u);   // RNE
    return (unsigned short)(r >> 16);
}

// x [16384,256] fp32 -> bf16, 8 elements/thread, fully coalesced.
__global__ void conv_x_kernel(const float* __restrict__ x,
                              unsigned short* __restrict__ xb) {
    const int t = blockIdx.x * 256 + threadIdx.x;      // 524288 threads
    const float4* p = (const float4*)x;
    float4 a = p[2 * t], b = p[2 * t + 1];
    ushort8 v;
    v[0] = f2bf(a.x); v[1] = f2bf(a.y); v[2] = f2bf(a.z); v[3] = f2bf(a.w);
    v[4] = f2bf(b.x); v[5] = f2bf(b.y); v[6] = f2bf(b.z); v[7] = f2bf(b.w);
    *(ushort8*)(xb + (size_t)t * 8) = v;
}

// W [32,4096,8] fp32 -> Bt [4096,256] bf16, Bt[o][s*8+c] = W[s][o][c].
// Thread t: s = t>>12, o = t&4095 -> consecutive threads read contiguous 32B.
__global__ void pack_w_kernel(const float* __restrict__ W,
                              unsigned short* __restrict__ wb) {
    const int t = blockIdx.x * 256 + threadIdx.x;      // 131072 threads
    const int s = t >> 12;                             // 0..31
    const int o = t & 4095;
    const float4* p = (const float4*)(W + (size_t)s * 32768 + (size_t)o * 8);
    float4 a = p[0], b = p[1];
    ushort8 v;
    v[0] = f2bf(a.x); v[1] = f2bf(a.y); v[2] = f2bf(a.z); v[3] = f2bf(a.w);
    v[4] = f2bf(b.x); v[5] = f2bf(b.y); v[6] = f2bf(b.z); v[7] = f2bf(b.w);
    *(ushort8*)(wb + (size_t)o * 256 + (size_t)s * 8) = v;
}

__device__ __forceinline__ void gload_lds16(const unsigned short* g, unsigned short* l) {
    __builtin_amdgcn_global_load_lds(
        (const __attribute__((address_space(1))) unsigned int*)(const void*)g,
        (__attribute__((address_space(3))) unsigned int*)(void*)l,
        16, 0, 0);
}

// C[M=16384, N=4096] fp32 = A[M,256]bf16 * Bt[N,256]bf16^T
// 128x128 tile, BK=32, 4 waves in 2x2, each wave 64x64 via 4x4 of 16x16x32 MFMA.
__global__ __launch_bounds__(256) void gemm_kernel(
    const unsigned short* __restrict__ A,
    const unsigned short* __restrict__ Bt,
    float* __restrict__ C) {
    __shared__ __align__(16) unsigned short lsA[128 * 32];   // 8 KB
    __shared__ __align__(16) unsigned short lsB[128 * 32];   // 8 KB

    const int tid  = threadIdx.x;
    const int wave = tid >> 6;
    const int lane = tid & 63;
    const int bm   = blockIdx.y;     // 0..127
    const int bn   = blockIdx.x;     // 0..31

    // --- staging addressing (global_load_lds: wave-uniform LDS base + lane*16) ---
    // thread covers tile row sr = tid>>2, 16B chunk (tid&3), XOR-swizzled by (row>>1)&3
    // so that ds_read_b128 fragment reads are 2-way (free) instead of 8-way conflicted.
    const int sr  = tid >> 2;                                  // 0..63
    const int scc = ((tid & 3) ^ ((tid >> 3) & 3)) * 8;        // swizzled chunk, elements
    const unsigned short* Ag = A  + ((size_t)(bm * 128 + sr)) * 256 + scc;
    const unsigned short* Bg = Bt + ((size_t)(bn * 128 + sr)) * 256 + scc;

    unsigned short* lA0 = &lsA[wave * 512];          // issue 0: tile rows [0,64)
    unsigned short* lA1 = &lsA[2048 + wave * 512];   // issue 1: tile rows [64,128)
    unsigned short* lB0 = &lsB[wave * 512];
    unsigned short* lB1 = &lsB[2048 + wave * 512];

    // --- fragment addressing ---
    const int wrow = wave >> 1, wcol = wave & 1;
    const int fr = lane & 15;        // row within 16x16 tile (A-m / B-n)
    const int fq = lane >> 4;        // k-group 0..3
    const int cs = (fq ^ ((fr >> 1) & 3)) * 8;       // un-swizzle chunk
    const unsigned short* aF = &lsA[(wrow * 64 + fr) * 32] + cs;
    const unsigned short* bF = &lsB[(wcol * 64 + fr) * 32] + cs;

    floatx4 acc[4][4] = {};

    for (int kt = 0; kt < 8; ++kt) {
        const int ko = kt * 32;
        gload_lds16(Ag + ko,             lA0);
        gload_lds16(Ag + ko + 64 * 256,  lA1);
        gload_lds16(Bg + ko,             lB0);
        gload_lds16(Bg + ko + 64 * 256,  lB1);
        __syncthreads();

        bf16x8 af[4], bfv[4];
#pragma unroll
        for (int i = 0; i < 4; ++i) {
            af[i]  = *(const bf16x8*)(const void*)(aF + i * 16 * 32);
            bfv[i] = *(const bf16x8*)(const void*)(bF + i * 16 * 32);
        }
#pragma unroll
        for (int i = 0; i < 4; ++i)
#pragma unroll
            for (int j = 0; j < 4; ++j)
                acc[i][j] = __builtin_amdgcn_mfma_f32_16x16x32_bf16(
                    af[i], bfv[j], acc[i][j], 0, 0, 0);
        __syncthreads();
    }

    // --- epilogue: C/D layout col = lane&15, row = (lane>>4)*4 + reg ---
    const int row0 = bm * 128 + wrow * 64 + fq * 4;
    const int col0 = bn * 128 + wcol * 64 + fr;
#pragma unroll
    for (int i = 0; i < 4; ++i) {
#pragma unroll
        for (int j = 0; j < 4; ++j) {
            float* Cp = C + (size_t)(row0 + i * 16) * 4096 + col0 + j * 16;
#pragma unroll
            for (int r = 0; r < 4; ++r)
                Cp[(size_t)r * 4096] = acc[i][j][r];
        }
    }
}

extern "C" void kernel_launch(void* const* d_in, const int* in_sizes, int n_in,
                              void* d_out, int out_size, void* d_ws, size_t ws_size,
                              hipStream_t stream) {
    const float* x = (const float*)d_in[0];   // [16384, 256]
    const float* W = (const float*)d_in[1];   // [32, 4096, 8]
    float* out = (float*)d_out;               // [16384, 4096]

    unsigned short* xb = (unsigned short*)d_ws;            // 8 MB
    unsigned short* wb = xb + (size_t)16384 * 256;         // +2 MB = 10 MB total

    conv_x_kernel<<<2048, 256, 0, stream>>>(x, xb);
    pack_w_kernel<<<512, 256, 0, stream>>>(W, wb);

    dim3 grid(32, 128);   // bn = 4096/128, bm = 16384/128
    gemm_kernel<<<grid, 256, 0, stream>>>(xb, wb, out);
}